// Round 1
// baseline (418.749 us; speedup 1.0000x reference)
//
#include <hip/hip_runtime.h>
#include <hip/hip_bf16.h>
#include <stdint.h>

#define NTOK 16384
#define DDIM 4096
#define NEXP 128
#define BM 32
#define BK 64
#define BKP 72  // padded LDS row stride in bf16 elems (144 B = 9*16B, keeps ds_read_b128 aligned, breaks pow2 bank stride)

typedef __attribute__((ext_vector_type(8))) short short8;   // 8 bf16 = 4 VGPRs (MFMA A/B frag)
typedef __attribute__((ext_vector_type(4))) float f32x4;    // MFMA C/D frag

// fp32 -> (hi, lo) bf16 pair, both RNE. f ~= hi + lo with |err| <~ 2^-17 |f|.
// f - fp32(hi) is exact (Sterbenz: exponent drops >= 8 bits, fits in 24-bit mantissa).
__device__ __forceinline__ void split_bf16(float f, uint32_t& h, uint32_t& l) {
    uint32_t u = __float_as_uint(f);
    h = (u + 0x7FFFu + ((u >> 16) & 1u)) >> 16;
    float r = f - __uint_as_float(h << 16);
    uint32_t v = __float_as_uint(r);
    l = (v + 0x7FFFu + ((v >> 16) & 1u)) >> 16;
}

// ---- kernel 1: split wg_weight [128][4096] fp32 -> w_hi, w_lo bf16 in ws ----
__global__ void prep_w(const float* __restrict__ w,
                       uint16_t* __restrict__ whi, uint16_t* __restrict__ wlo) {
    int i = (blockIdx.x * blockDim.x + threadIdx.x) * 4;
    float4 f = *(const float4*)(w + i);
    uint32_t h0, h1, h2, h3, l0, l1, l2, l3;
    split_bf16(f.x, h0, l0);
    split_bf16(f.y, h1, l1);
    split_bf16(f.z, h2, l2);
    split_bf16(f.w, h3, l3);
    uint2 hv = make_uint2(h0 | (h1 << 16), h2 | (h3 << 16));
    uint2 lv = make_uint2(l0 | (l1 << 16), l2 | (l3 << 16));
    *(uint2*)(whi + i) = hv;
    *(uint2*)(wlo + i) = lv;
}

// ---- kernel 2: logits = x @ w^T via split-bf16 3-product MFMA ----
// BM=32 tokens x 128 experts per block, 4 waves each own 32 tokens x 32 experts.
__global__ __launch_bounds__(256, 2) void gemm_logits(
    const float* __restrict__ x,
    const uint16_t* __restrict__ whi, const uint16_t* __restrict__ wlo,
    float* __restrict__ S)
{
    __shared__ uint16_t sAh[BM * BKP], sAl[BM * BKP];
    __shared__ uint16_t sBh[NEXP * BKP], sBl[NEXP * BKP];

    const int tid  = threadIdx.x;
    const int lane = tid & 63;
    const int wave = tid >> 6;
    const int m0   = blockIdx.x * BM;

    // A staging: thread t handles row am = t>>3, 8-elem k-chunk akc = t&7
    const int am  = tid >> 3;
    const int akc = tid & 7;
    const float* xp = x + (size_t)(m0 + am) * DDIM + akc * 8;

    f32x4 acc[2][2];
    #pragma unroll
    for (int mt = 0; mt < 2; ++mt)
        #pragma unroll
        for (int nt = 0; nt < 2; ++nt)
            acc[mt][nt] = (f32x4){0.f, 0.f, 0.f, 0.f};

    const int q = lane >> 4;   // quad id, k-group selector for A/B frags
    const int c = lane & 15;   // row (A) / col (B) within 16

    for (int k0 = 0; k0 < DDIM; k0 += BK) {
        // ---- stage A: fp32 global -> split bf16 hi/lo -> LDS ----
        float4 fa = *(const float4*)(xp + k0);
        float4 fb = *(const float4*)(xp + k0 + 4);
        uint32_t h[8], l[8];
        split_bf16(fa.x, h[0], l[0]); split_bf16(fa.y, h[1], l[1]);
        split_bf16(fa.z, h[2], l[2]); split_bf16(fa.w, h[3], l[3]);
        split_bf16(fb.x, h[4], l[4]); split_bf16(fb.y, h[5], l[5]);
        split_bf16(fb.z, h[6], l[6]); split_bf16(fb.w, h[7], l[7]);
        uint4 hv = make_uint4(h[0] | (h[1] << 16), h[2] | (h[3] << 16),
                              h[4] | (h[5] << 16), h[6] | (h[7] << 16));
        uint4 lv = make_uint4(l[0] | (l[1] << 16), l[2] | (l[3] << 16),
                              l[4] | (l[5] << 16), l[6] | (l[7] << 16));
        *(uint4*)&sAh[am * BKP + akc * 8] = hv;
        *(uint4*)&sAl[am * BKP + akc * 8] = lv;

        // ---- stage B: pre-split bf16 from ws (L2-resident) -> LDS ----
        #pragma unroll
        for (int i = 0; i < 4; ++i) {
            int ch = tid + i * 256;           // 1024 chunks of 8 bf16
            int n = ch >> 3, kc = ch & 7;
            const size_t go = (size_t)n * DDIM + k0 + kc * 8;
            uint4 bh = *(const uint4*)(whi + go);
            uint4 bl = *(const uint4*)(wlo + go);
            *(uint4*)&sBh[n * BKP + kc * 8] = bh;
            *(uint4*)&sBl[n * BKP + kc * 8] = bl;
        }
        __syncthreads();

        // ---- compute: 2 k-steps of 32, 2x2 tiles, 3 MFMAs each ----
        #pragma unroll
        for (int ks = 0; ks < 2; ++ks) {
            const int kb = ks * 32 + q * 8;
            short8 ah[2], alo[2], bh[2], blo[2];
            #pragma unroll
            for (int mt = 0; mt < 2; ++mt) {
                const int ro = (mt * 16 + c) * BKP + kb;
                ah[mt]  = *(const short8*)&sAh[ro];
                alo[mt] = *(const short8*)&sAl[ro];
            }
            #pragma unroll
            for (int nt = 0; nt < 2; ++nt) {
                const int ro = (wave * 32 + nt * 16 + c) * BKP + kb;
                bh[nt]  = *(const short8*)&sBh[ro];
                blo[nt] = *(const short8*)&sBl[ro];
            }
            #pragma unroll
            for (int mt = 0; mt < 2; ++mt)
                #pragma unroll
                for (int nt = 0; nt < 2; ++nt) {
                    acc[mt][nt] = __builtin_amdgcn_mfma_f32_16x16x32_bf16(alo[mt], bh[nt],  acc[mt][nt], 0, 0, 0);
                    acc[mt][nt] = __builtin_amdgcn_mfma_f32_16x16x32_bf16(ah[mt],  blo[nt], acc[mt][nt], 0, 0, 0);
                    acc[mt][nt] = __builtin_amdgcn_mfma_f32_16x16x32_bf16(ah[mt],  bh[nt],  acc[mt][nt], 0, 0, 0);
                }
        }
        __syncthreads();
    }

    // ---- epilogue: C/D layout col=lane&15, row=(lane>>4)*4+reg (m89-verified) ----
    #pragma unroll
    for (int mt = 0; mt < 2; ++mt)
        #pragma unroll
        for (int nt = 0; nt < 2; ++nt) {
            const int e = wave * 32 + nt * 16 + c;
            #pragma unroll
            for (int r = 0; r < 4; ++r) {
                const int tok = m0 + mt * 16 + q * 4 + r;
                S[(size_t)tok * NEXP + e] = acc[mt][nt][r];
            }
        }
}

// ---- kernel 3: masked softmax + adaptive top-k, one wave per token ----
__global__ __launch_bounds__(256) void postproc(
    float* __restrict__ S, const float* __restrict__ mask,
    float* __restrict__ topk_out)
{
    const int lane = threadIdx.x & 63;
    const int wave = threadIdx.x >> 6;
    const int t = blockIdx.x * 4 + wave;
    float* row = S + (size_t)t * NEXP;

    float s0 = row[lane], s1 = row[lane + 64];
    float mk0 = mask[lane], mk1 = mask[lane + 64];
    const bool a0 = (mk0 != 0.f), a1 = (mk1 != 0.f);

    // max over active logits
    float mx = fmaxf(a0 ? s0 : -3.0e38f, a1 ? s1 : -3.0e38f);
    #pragma unroll
    for (int off = 32; off; off >>= 1) mx = fmaxf(mx, __shfl_xor(mx, off));

    float p0 = a0 ? __expf(s0 - mx) : 0.f;
    float p1 = a1 ? __expf(s1 - mx) : 0.f;
    float sum = p0 + p1;
    #pragma unroll
    for (int off = 32; off; off >>= 1) sum += __shfl_xor(sum, off);

    const float inv = 1.0f / sum;
    const float sc0 = p0 * inv + 1e-14f;
    const float sc1 = p1 * inv + 1e-14f;
    row[lane]      = sc0;
    row[lane + 64] = sc1;

    const int active = __popcll(__ballot(a0)) + __popcll(__ballot(a1));

    // adaptive top-k: extract maxima until cumulative mass >= 0.5.
    // Sequential adds in descending order == reference's sorted cumsum order.
    float v0 = sc0, v1 = sc1;
    float cum = 0.f;
    int k = 0;
    while (cum < 0.5f && k < NEXP) {
        float mv = fmaxf(v0, v1);
        #pragma unroll
        for (int off = 32; off; off >>= 1) mv = fmaxf(mv, __shfl_xor(mv, off));
        cum += mv;
        ++k;
        // remove exactly one instance of the max (ties handled one at a time)
        unsigned long long b = __ballot(v0 == mv || v1 == mv);
        int first = __ffsll(b) - 1;
        if (lane == first) {
            if (v0 == mv) v0 = -1.f; else v1 = -1.f;
        }
    }
    int topk = k < active ? k : active;
    if (lane == 0) topk_out[t] = (float)topk;
}

extern "C" void kernel_launch(void* const* d_in, const int* in_sizes, int n_in,
                              void* d_out, int out_size, void* d_ws, size_t ws_size,
                              hipStream_t stream) {
    (void)in_sizes; (void)n_in; (void)out_size; (void)ws_size;
    const float* x    = (const float*)d_in[0];
    const float* w    = (const float*)d_in[1];
    const float* mask = (const float*)d_in[2];

    float* S    = (float*)d_out;                  // [16384,128] scores (also logit scratch)
    float* topk = S + (size_t)NTOK * NEXP;        // [16384] top_k as float

    uint16_t* whi = (uint16_t*)d_ws;              // [128,4096] bf16 hi
    uint16_t* wlo = whi + (size_t)NEXP * DDIM;    // [128,4096] bf16 lo

    hipLaunchKernelGGL(prep_w, dim3((NEXP * DDIM) / (256 * 4)), dim3(256), 0, stream,
                       w, whi, wlo);
    hipLaunchKernelGGL(gemm_logits, dim3(NTOK / BM), dim3(256), 0, stream,
                       x, whi, wlo, S);
    hipLaunchKernelGGL(postproc, dim3(NTOK / 4), dim3(256), 0, stream,
                       S, mask, topk);
}